// Round 1
// baseline (39.193 us; speedup 1.0000x reference)
//
#include <hip/hip_runtime.h>

// Structural constants (mirror reference)
#define NPOSE 64
#define NROT  128
#define NATOM 8
#define EPS   1e-2f

// LDS layout: component-major [24][NROT], padded row stride to break bank alignment
#define RSTR 132

__global__ __launch_bounds__(256) void rot_score_kernel(
    const float* __restrict__ coords,
    float* __restrict__ out)
{
    __shared__ float lds[24 * RSTR];

    const int p     = blockIdx.x >> 6;   // 64 i-tiles per pose
    const int itile = blockIdx.x & 63;
    const int tid   = threadIdx.x;

    // Stage this pose's coords: 3072 contiguous floats at coords[p*NROT*NATOM*3].
    // Global reads coalesced; LDS writes transposed to component-major.
    const float* src = coords + (size_t)p * (NROT * NATOM * 3);
    for (int idx = tid; idx < NROT * NATOM * 3; idx += 256) {
        int r   = idx / 24;          // rotamer within pose
        int rem = idx - r * 24;      // a*3 + c
        lds[rem * RSTR + r] = src[idx];
    }
    __syncthreads();

    const int li = tid >> 7;             // 0..1
    const int i  = itile * 2 + li;       // rotamer i within pose
    const int j  = tid & 127;            // rotamer j within pose

    // Pull both rotamers' atoms into registers.
    float xi[24], xj[24];
#pragma unroll
    for (int k = 0; k < 24; ++k) {
        xi[k] = lds[k * RSTR + i];   // wave-uniform -> LDS broadcast
        xj[k] = lds[k * RSTR + j];   // consecutive lanes -> conflict-free
    }

    float s0 = 0.0f, s1 = 0.0f;
    const float NEG_LOG2E = -1.44269504088896340736f;
#pragma unroll
    for (int a = 0; a < NATOM; ++a) {
#pragma unroll
        for (int b = 0; b < NATOM; ++b) {
            float dx = xi[a * 3 + 0] - xj[b * 3 + 0];
            float dy = xi[a * 3 + 1] - xj[b * 3 + 1];
            float dz = xi[a * 3 + 2] - xj[b * 3 + 2];
            float d2 = dx * dx + dy * dy + dz * dz;
            d2 = fmaxf(d2, EPS);
            s0 += __builtin_amdgcn_rcpf(d2);                     // 1/d2
            float nd = __builtin_amdgcn_sqrtf(d2);               // sqrt(d2)
            s1 += __builtin_amdgcn_exp2f(nd * NEG_LOG2E);        // exp(-sqrt(d2))
        }
    }

    const int nnz = NPOSE * NROT * NROT;
    const int n   = ((p * NROT) + i) * NROT + j;

    out[0 * nnz + n] = s0;
    out[1 * nnz + n] = s1;
    out[2 * nnz + n] = (float)p;
    out[3 * nnz + n] = (float)(p * NROT + i);
    out[4 * nnz + n] = (float)(p * NROT + j);
}

extern "C" void kernel_launch(void* const* d_in, const int* in_sizes, int n_in,
                              void* d_out, int out_size, void* d_ws, size_t ws_size,
                              hipStream_t stream) {
    (void)in_sizes; (void)n_in; (void)d_ws; (void)ws_size; (void)out_size;
    const float* coords = (const float*)d_in[0];
    float* out = (float*)d_out;

    dim3 grid(NPOSE * 64);   // 64 poses x 64 i-tiles (2 rows each)
    dim3 block(256);
    rot_score_kernel<<<grid, block, 0, stream>>>(coords, out);
}

// Round 2
// 24.341 us; speedup vs baseline: 1.6102x; 1.6102x over previous
//
#include <hip/hip_runtime.h>

// Structural constants (mirror reference)
#define NPOSE 64
#define NROT  128
#define NATOM 8
#define EPS   1e-2f

#define TS    16                 // rotamer tile size
#define NTILE (NROT / TS)        // 8 tiles per axis
#define NPAIR (NTILE * (NTILE + 1) / 2)   // 36 tile pairs (ti <= tj)
#define CSTR  25                 // coord LDS row stride (24 floats + 1 pad, coprime w/ 32)
#define SSTR  17                 // result tile row stride (16 + 1 pad)

__global__ __launch_bounds__(256, 8) void rot_score_kernel(
    const float* __restrict__ coords,
    float* __restrict__ out)
{
    __shared__ float ldsI[TS * CSTR];
    __shared__ float ldsJ[TS * CSTR];
    __shared__ float res0[TS * SSTR];
    __shared__ float res1[TS * SSTR];

    const int bid = blockIdx.x;
    const int p   = bid / NPAIR;
    int t = bid - p * NPAIR;
    int ti = 0;
    while (t >= NTILE - ti) { t -= NTILE - ti; ++ti; }   // unrank upper triangle
    const int tj = ti + t;

    const int tid = threadIdx.x;
    const float* src = coords + (size_t)p * (NROT * NATOM * 3);

    // Stage the two 16-rotamer coordinate sets (16 x 24 floats each), coalesced.
    for (int idx = tid; idx < 2 * TS * 24; idx += 256) {
        const int set = idx >= TS * 24;
        const int loc = idx - set * (TS * 24);
        const int r   = loc / 24;
        const int k   = loc - r * 24;
        const float v = src[(set ? tj : ti) * (TS * 24) + loc];
        (set ? ldsJ : ldsI)[r * CSTR + k] = v;
    }
    __syncthreads();

    const int ty = tid >> 4;    // i within tile (0..15)
    const int tx = tid & 15;    // j within tile (0..15)

    // i-rotamer atoms in registers (wave reads are 4-address broadcasts)
    float xi[24];
#pragma unroll
    for (int k = 0; k < 24; ++k) xi[k] = ldsI[ty * CSTR + k];

    const float NEG_LOG2E = -1.44269504088896340736f;
    float s0a = 0.0f, s0b = 0.0f, s1a = 0.0f, s1b = 0.0f;

#pragma unroll
    for (int b = 0; b < NATOM; ++b) {
        const float jx = ldsJ[tx * CSTR + b * 3 + 0];
        const float jy = ldsJ[tx * CSTR + b * 3 + 1];
        const float jz = ldsJ[tx * CSTR + b * 3 + 2];
#pragma unroll
        for (int a = 0; a < NATOM; ++a) {
            const float dx = xi[a * 3 + 0] - jx;
            const float dy = xi[a * 3 + 1] - jy;
            const float dz = xi[a * 3 + 2] - jz;
            float d2 = fmaf(dx, dx, fmaf(dy, dy, dz * dz));
            d2 = fmaxf(d2, EPS);
            const float rs  = __builtin_amdgcn_rsqf(d2);   // 1/sqrt(d2)
            const float arg = (d2 * NEG_LOG2E) * rs;       // -log2e * sqrt(d2)
            if (a & 1) { s0a = fmaf(rs, rs, s0a); s1a += __builtin_amdgcn_exp2f(arg); }
            else       { s0b = fmaf(rs, rs, s0b); s1b += __builtin_amdgcn_exp2f(arg); }
        }
    }
    const float s0 = s0a + s0b;
    const float s1 = s1a + s1b;

    // Stage results for the coalesced mirror write.
    res0[ty * SSTR + tx] = s0;
    res1[ty * SSTR + tx] = s1;

    const int nnz = NPOSE * NROT * NROT;
    const int gi  = ti * TS + ty;
    const int gj  = tj * TS + tx;
    const int n   = (p * NROT + gi) * NROT + gj;

    out[0 * nnz + n] = s0;
    out[1 * nnz + n] = s1;
    out[2 * nnz + n] = (float)p;
    out[3 * nnz + n] = (float)(p * NROT + gi);
    out[4 * nnz + n] = (float)(p * NROT + gj);

    if (ti != tj) {              // block-uniform branch
        __syncthreads();
        const float m0 = res0[tx * SSTR + ty];   // value of pair (ti*TS+tx, tj*TS+ty)
        const float m1 = res1[tx * SSTR + ty];
        const int mi = tj * TS + ty;
        const int mj = ti * TS + tx;
        const int nm = (p * NROT + mi) * NROT + mj;
        out[0 * nnz + nm] = m0;
        out[1 * nnz + nm] = m1;
        out[2 * nnz + nm] = (float)p;
        out[3 * nnz + nm] = (float)(p * NROT + mi);
        out[4 * nnz + nm] = (float)(p * NROT + mj);
    }
}

extern "C" void kernel_launch(void* const* d_in, const int* in_sizes, int n_in,
                              void* d_out, int out_size, void* d_ws, size_t ws_size,
                              hipStream_t stream) {
    (void)in_sizes; (void)n_in; (void)d_ws; (void)ws_size; (void)out_size;
    const float* coords = (const float*)d_in[0];
    float* out = (float*)d_out;

    dim3 grid(NPOSE * NPAIR);   // 64 poses x 36 upper-triangle tile pairs = 2304 blocks
    dim3 block(256);
    rot_score_kernel<<<grid, block, 0, stream>>>(coords, out);
}

// Round 3
// 23.869 us; speedup vs baseline: 1.6420x; 1.0198x over previous
//
#include <hip/hip_runtime.h>

// Structural constants (mirror reference)
#define NPOSE 64
#define NROT  128
#define NATOM 8
#define EPS   1e-2f

#define TS    16                 // rotamer tile size
#define NTILE (NROT / TS)        // 8 tiles per axis
#define NPAIR (NTILE * (NTILE + 1) / 2)   // 36 tile pairs (ti <= tj)
#define CSTR  25                 // coord LDS row stride (24 floats + 1 pad, coprime w/ 32)
#define SSTR  17                 // result tile row stride (16 + 1 pad)

__global__ __launch_bounds__(256, 4) void rot_score_kernel(
    const float* __restrict__ coords,
    float* __restrict__ out)
{
    __shared__ float ldsI[TS * CSTR];
    __shared__ float ldsJ[TS * CSTR];
    __shared__ float res0[TS * SSTR];
    __shared__ float res1[TS * SSTR];

    const int bid = blockIdx.x;
    const int p   = bid / NPAIR;
    int t = bid - p * NPAIR;
    int ti = 0;
    while (t >= NTILE - ti) { t -= NTILE - ti; ++ti; }   // unrank upper triangle
    const int tj = ti + t;

    const int tid = threadIdx.x;
    const float* src = coords + (size_t)p * (NROT * NATOM * 3);

    // Stage the two 16-rotamer coordinate sets (16 x 24 floats each), coalesced.
    for (int idx = tid; idx < 2 * TS * 24; idx += 256) {
        const int set = idx >= TS * 24;
        const int loc = idx - set * (TS * 24);
        const int r   = loc / 24;
        const int k   = loc - r * 24;
        const float v = src[(set ? tj : ti) * (TS * 24) + loc];
        (set ? ldsJ : ldsI)[r * CSTR + k] = v;
    }
    __syncthreads();

    const int ty = tid >> 4;    // i within tile (0..15)
    const int tx = tid & 15;    // j within tile (0..15)

    // Both rotamers' atoms fully in registers -> inner loop has zero LDS traffic.
    float xi[24], xj[24];
#pragma unroll
    for (int k = 0; k < 24; ++k) xi[k] = ldsI[ty * CSTR + k];   // broadcast reads
#pragma unroll
    for (int k = 0; k < 24; ++k) xj[k] = ldsJ[tx * CSTR + k];   // conflict-free (stride 25)

    // Per-atom squared norms (hoisted out of the 8x8 loop).
    float sqi[NATOM], sqj[NATOM];
#pragma unroll
    for (int a = 0; a < NATOM; ++a) {
        sqi[a] = fmaf(xi[a*3+2], xi[a*3+2], fmaf(xi[a*3+1], xi[a*3+1], xi[a*3+0]*xi[a*3+0]));
        sqj[a] = fmaf(xj[a*3+2], xj[a*3+2], fmaf(xj[a*3+1], xj[a*3+1], xj[a*3+0]*xj[a*3+0]));
    }

    const float NEG_LOG2E = -1.44269504088896340736f;
    float s0a = 0.0f, s0b = 0.0f, s1a = 0.0f, s1b = 0.0f;

#pragma unroll
    for (int b = 0; b < NATOM; ++b) {
#pragma unroll
        for (int a = 0; a < NATOM; ++a) {
            // d2 = |xi_a|^2 + |xj_b|^2 - 2 xi.xj
            float dot = xi[a*3+0] * xj[b*3+0];
            dot = fmaf(xi[a*3+1], xj[b*3+1], dot);
            dot = fmaf(xi[a*3+2], xj[b*3+2], dot);
            float d2 = fmaf(-2.0f, dot, sqi[a] + sqj[b]);
            d2 = fmaxf(d2, EPS);
            const float rs  = __builtin_amdgcn_rsqf(d2);   // 1/sqrt(d2)
            const float arg = (d2 * NEG_LOG2E) * rs;       // -log2e * sqrt(d2)
            if (a & 1) { s0a = fmaf(rs, rs, s0a); s1a += __builtin_amdgcn_exp2f(arg); }
            else       { s0b = fmaf(rs, rs, s0b); s1b += __builtin_amdgcn_exp2f(arg); }
        }
    }
    const float s0 = s0a + s0b;
    const float s1 = s1a + s1b;

    // Stage results for the coalesced mirror write.
    res0[ty * SSTR + tx] = s0;
    res1[ty * SSTR + tx] = s1;

    const int nnz = NPOSE * NROT * NROT;
    const int gi  = ti * TS + ty;
    const int gj  = tj * TS + tx;
    const int n   = (p * NROT + gi) * NROT + gj;

    out[0 * nnz + n] = s0;
    out[1 * nnz + n] = s1;
    out[2 * nnz + n] = (float)p;
    out[3 * nnz + n] = (float)(p * NROT + gi);
    out[4 * nnz + n] = (float)(p * NROT + gj);

    if (ti != tj) {              // block-uniform branch
        __syncthreads();
        const float m0 = res0[tx * SSTR + ty];   // value of pair (ti*TS+tx, tj*TS+ty)
        const float m1 = res1[tx * SSTR + ty];
        const int mi = tj * TS + ty;
        const int mj = ti * TS + tx;
        const int nm = (p * NROT + mi) * NROT + mj;
        out[0 * nnz + nm] = m0;
        out[1 * nnz + nm] = m1;
        out[2 * nnz + nm] = (float)p;
        out[3 * nnz + nm] = (float)(p * NROT + mi);
        out[4 * nnz + nm] = (float)(p * NROT + mj);
    }
}

extern "C" void kernel_launch(void* const* d_in, const int* in_sizes, int n_in,
                              void* d_out, int out_size, void* d_ws, size_t ws_size,
                              hipStream_t stream) {
    (void)in_sizes; (void)n_in; (void)d_ws; (void)ws_size; (void)out_size;
    const float* coords = (const float*)d_in[0];
    float* out = (float*)d_out;

    dim3 grid(NPOSE * NPAIR);   // 64 poses x 36 upper-triangle tile pairs = 2304 blocks
    dim3 block(256);
    rot_score_kernel<<<grid, block, 0, stream>>>(coords, out);
}

// Round 4
// 20.026 us; speedup vs baseline: 1.9571x; 1.1919x over previous
//
#include <hip/hip_runtime.h>

typedef float v2f __attribute__((ext_vector_type(2)));

// Structural constants (mirror reference)
#define NPOSE 64
#define NROT  128
#define NATOM 8
#define EPS   1e-2f

#define TS    16                 // rotamer tile size
#define NTILE (NROT / TS)        // 8 tiles per axis
#define NPAIR (NTILE * (NTILE + 1) / 2)   // 36 tile pairs (ti <= tj)
#define CSTR  28                 // coord LDS row stride: 24 floats + 4 pad -> 112B, 16B-aligned rows
#define SSTR  17                 // result tile row stride (16 + 1 pad)

__global__ __launch_bounds__(256, 4) void rot_score_kernel(
    const float* __restrict__ coords,
    float* __restrict__ out)
{
    __shared__ float ldsI[TS * CSTR];
    __shared__ float ldsJ[TS * CSTR];
    __shared__ float res0[TS * SSTR];
    __shared__ float res1[TS * SSTR];

    const int bid = blockIdx.x;
    const int p   = bid / NPAIR;
    int t = bid - p * NPAIR;
    int ti = 0;
    while (t >= NTILE - ti) { t -= NTILE - ti; ++ti; }   // unrank upper triangle
    const int tj = ti + t;

    const int tid = threadIdx.x;
    const float* src = coords + (size_t)p * (NROT * NATOM * 3);

    // Stage the two 16-rotamer coordinate sets (16 x 24 floats each), coalesced reads.
    for (int idx = tid; idx < 2 * TS * 24; idx += 256) {
        const int set = idx >= TS * 24;
        const int loc = idx - set * (TS * 24);
        const int r   = loc / 24;
        const int k   = loc - r * 24;
        const float v = src[(set ? tj : ti) * (TS * 24) + loc];
        (set ? ldsJ : ldsI)[r * CSTR + k] = v;
    }
    __syncthreads();

    const int ty = tid >> 4;    // i within tile (0..15)
    const int tx = tid & 15;    // j within tile (0..15)

    // Vector LDS reads: 6x ds_read_b128 per rotamer (rows are 16B-aligned).
    float4 xi4[6], xj4[6];
    {
        const float4* rowI = (const float4*)&ldsI[ty * CSTR];
        const float4* rowJ = (const float4*)&ldsJ[tx * CSTR];
#pragma unroll
        for (int k = 0; k < 6; ++k) { xi4[k] = rowI[k]; xj4[k] = rowJ[k]; }
    }
    const float* xi = (const float*)xi4;
    const float* xj = (const float*)xj4;

    // Per-atom squared norms for i (scalar), and packed j-pairs (atoms 2bp, 2bp+1).
    float sqi[NATOM];
#pragma unroll
    for (int a = 0; a < NATOM; ++a)
        sqi[a] = fmaf(xi[a*3+2], xi[a*3+2], fmaf(xi[a*3+1], xi[a*3+1], xi[a*3+0]*xi[a*3+0]));

    v2f jx[4], jy[4], jz[4], sj[4];
#pragma unroll
    for (int bp = 0; bp < 4; ++bp) {
        v2f ax = { xj[bp*6 + 0], xj[bp*6 + 3] };
        v2f ay = { xj[bp*6 + 1], xj[bp*6 + 4] };
        v2f az = { xj[bp*6 + 2], xj[bp*6 + 5] };
        sj[bp] = __builtin_elementwise_fma(az, az, __builtin_elementwise_fma(ay, ay, ax*ax));
        jx[bp] = ax * -2.0f;     // fold the -2 of d2 = sqi + sqj - 2*dot
        jy[bp] = ay * -2.0f;
        jz[bp] = az * -2.0f;
    }

    const float NEG_LOG2E = -1.44269504088896340736f;
    v2f s0v = { 0.0f, 0.0f }, s1v = { 0.0f, 0.0f };
    const v2f veps = { EPS, EPS };

#pragma unroll
    for (int bp = 0; bp < 4; ++bp) {
#pragma unroll
        for (int a = 0; a < NATOM; ++a) {
            v2f t = sj[bp] + sqi[a];                               // pk_add (splat)
            v2f cx = xi[a*3+0], cy = xi[a*3+1], cz = xi[a*3+2];    // splats
            t = __builtin_elementwise_fma(cx, jx[bp], t);
            t = __builtin_elementwise_fma(cy, jy[bp], t);
            t = __builtin_elementwise_fma(cz, jz[bp], t);          // t = d2 pair
            t = __builtin_elementwise_max(t, veps);
            v2f rs = { __builtin_amdgcn_rsqf(t.x), __builtin_amdgcn_rsqf(t.y) };
            s0v = __builtin_elementwise_fma(rs, rs, s0v);          // += 1/d2
            v2f arg = (t * NEG_LOG2E) * rs;                        // -log2e*sqrt(d2)
            v2f e = { __builtin_amdgcn_exp2f(arg.x), __builtin_amdgcn_exp2f(arg.y) };
            s1v += e;
        }
    }
    const float s0 = s0v.x + s0v.y;
    const float s1 = s1v.x + s1v.y;

    // Stage results for the coalesced mirror write.
    res0[ty * SSTR + tx] = s0;
    res1[ty * SSTR + tx] = s1;

    const int nnz = NPOSE * NROT * NROT;
    const int gi  = ti * TS + ty;
    const int gj  = tj * TS + tx;
    const int n   = (p * NROT + gi) * NROT + gj;

    out[0 * nnz + n] = s0;
    out[1 * nnz + n] = s1;
    out[2 * nnz + n] = (float)p;
    out[3 * nnz + n] = (float)(p * NROT + gi);
    out[4 * nnz + n] = (float)(p * NROT + gj);

    if (ti != tj) {              // block-uniform branch
        __syncthreads();
        const float m0 = res0[tx * SSTR + ty];   // value of pair (ti*TS+tx, tj*TS+ty)
        const float m1 = res1[tx * SSTR + ty];
        const int mi = tj * TS + ty;
        const int mj = ti * TS + tx;
        const int nm = (p * NROT + mi) * NROT + mj;
        out[0 * nnz + nm] = m0;
        out[1 * nnz + nm] = m1;
        out[2 * nnz + nm] = (float)p;
        out[3 * nnz + nm] = (float)(p * NROT + mi);
        out[4 * nnz + nm] = (float)(p * NROT + mj);
    }
}

extern "C" void kernel_launch(void* const* d_in, const int* in_sizes, int n_in,
                              void* d_out, int out_size, void* d_ws, size_t ws_size,
                              hipStream_t stream) {
    (void)in_sizes; (void)n_in; (void)d_ws; (void)ws_size; (void)out_size;
    const float* coords = (const float*)d_in[0];
    float* out = (float*)d_out;

    dim3 grid(NPOSE * NPAIR);   // 64 poses x 36 upper-triangle tile pairs = 2304 blocks
    dim3 block(256);
    rot_score_kernel<<<grid, block, 0, stream>>>(coords, out);
}